// Round 6
// baseline (73.052 us; speedup 1.0000x reference)
//
#include <hip/hip_runtime.h>
#include <math.h>

// d_in order: X[300000,256] f32, y[300000,1] f32, Z[1000,8] f32,
//             beta_w[1,256] f32, gamma_w[1,8] f32, theta[1] f32
// ws layout (bytes): [0..15] floats {s1,s2,v,r}; [32..159] float sL[32];
//                    [256..] double partials[nblocks]

typedef float f32x4 __attribute__((ext_vector_type(4)));

#define NT 256

__global__ __launch_bounds__(256) void k_scalars(const float* __restrict__ Z,
                                                 const float* __restrict__ gamma_w,
                                                 const float* __restrict__ theta,
                                                 float* __restrict__ ws,
                                                 int n_study) {
    __shared__ double red1[NT], red2[NT];
    __shared__ float rsh;
    int t = threadIdx.x;
    float g[8];
#pragma unroll
    for (int j = 0; j < 8; ++j) g[j] = gamma_w[j];
    double s1 = 0.0, s2 = 0.0;
    for (int s = t; s < n_study; s += NT) {
        float d = 0.f;
#pragma unroll
        for (int j = 0; j < 8; ++j) d = fmaf(Z[s * 8 + j], g[j], d);
        double mu = exp((double)d);
        s1 += mu;
        s2 += mu * mu;
    }
    red1[t] = s1;
    red2[t] = s2;
    __syncthreads();
    for (int off = NT / 2; off; off >>= 1) {
        if (t < off) { red1[t] += red1[t + off]; red2[t] += red2[t + off]; }
        __syncthreads();
    }
    if (t == 0) {
        double S1 = red1[0], S2 = red2[0];
        double th = (double)theta[0];
        double sig = 1.0 / (1.0 + exp(-th));
        double alpha = 100.0 * (double)n_study * sig + 1e-8;
        double est = alpha * S2 / (S1 * S1);  // mean(voxel_sum_alpha) is voxel-independent
        double v = 1.0 / est;
        double r = v * S1 * S1 / S2;
        ws[0] = (float)S1;
        ws[1] = (float)S2;
        ws[2] = (float)v;
        ws[3] = (float)r;
        rsh = (float)r;
    }
    __syncthreads();
    if (t < 32) {  // L[y] = lgamma(y+r)-lgamma(y+1)-lgamma(r) = sum_{k<y} log((r+k)/(k+1))
        float r = rsh;
        float acc = 0.f;
        for (int k = 0; k < t; ++k) acc += logf((r + (float)k) / (float)(k + 1));
        ws[8 + t] = acc;
    }
}

__global__ __launch_bounds__(256) void k_main(const f32x4* __restrict__ X4,
                                              const float* __restrict__ y,
                                              const f32x4* __restrict__ beta4,
                                              const float* __restrict__ ws,
                                              double* __restrict__ partials,
                                              int V) {
    const int t    = threadIdx.x;
    const int lane = t & 63;
    const int wib  = t >> 6;

    const float s1c = ws[0], s2c = ws[1], vc = ws[2], rc = ws[3];
    const float* sLg = ws + 8;

    const int wave = blockIdx.x * 4 + wib;
    const int row0 = wave << 6;
    double term = 0.0;

    if (row0 + 64 <= V) {
        const f32x4 b = beta4[lane];
        const f32x4* Xp = X4 + (size_t)row0 * 64 + lane;
        float dmine = 0.f;
        f32x4 xv[8], xn[8];
#pragma unroll
        for (int i = 0; i < 8; ++i) xv[i] = Xp[i * 64];
#pragma unroll
        for (int bb = 0; bb < 8; ++bb) {
            if (bb < 7) {
#pragma unroll
                for (int i = 0; i < 8; ++i)
                    xn[i] = Xp[((bb + 1) * 8 + i) * 64];
            }
            float d[8];
#pragma unroll
            for (int i = 0; i < 8; ++i)
                d[i] = fmaf(xv[i].x, b.x, fmaf(xv[i].y, b.y, fmaf(xv[i].z, b.z, xv[i].w * b.w)));
            // 3-level pairwise transpose-tree: after it, every lane holds the
            // 8-lane-group partial of row (8*bb + (lane&7)).
#pragma unroll
            for (int s = 1; s < 8; s <<= 1) {
#pragma unroll
                for (int j = 0; j < 8; j += 2 * s) {
                    float ta = __shfl_xor(d[j], s, 64);
                    float tb = __shfl_xor(d[j + s], s, 64);
                    d[j] = (lane & s) ? (d[j + s] + tb) : (d[j] + ta);
                }
            }
            float rs = d[0];
            rs += __shfl_xor(rs, 8, 64);
            rs += __shfl_xor(rs, 16, 64);
            rs += __shfl_xor(rs, 32, 64);   // full row sum, replicated per lane
            if ((lane >> 3) == bb) dmine = rs;  // lane l owns row row0+l
#pragma unroll
            for (int i = 0; i < 8; ++i) xv[i] = xn[i];
        }
        const float yv = y[row0 + lane];
        const float mu = expf(dmine);
        const float num = mu * mu * s2c;
        const float p = num / fmaf(vc * s1c, mu, num);
        int yi = (int)yv; yi = yi < 0 ? 0 : (yi > 31 ? 31 : yi);
        term = (double)(sLg[yi] + rc * log1pf(-p) + yv * logf(p));
    } else if (row0 < V) {  // tail wave
        const f32x4 b = beta4[lane];
        const int nrows = V - row0;
        const f32x4* Xp = X4 + (size_t)row0 * 64 + lane;
        float dmine = 0.f;
        for (int rr = 0; rr < nrows; ++rr) {
            f32x4 x = Xp[(size_t)rr * 64];
            float dd = fmaf(x.x, b.x, fmaf(x.y, b.y, fmaf(x.z, b.z, x.w * b.w)));
#pragma unroll
            for (int m = 32; m; m >>= 1) dd += __shfl_xor(dd, m, 64);
            if (lane == rr) dmine = dd;
        }
        if (lane < nrows) {
            const float yv = y[row0 + lane];
            const float mu = expf(dmine);
            const float num = mu * mu * s2c;
            const float p = num / fmaf(vc * s1c, mu, num);
            int yi = (int)yv; yi = yi < 0 ? 0 : (yi > 31 ? 31 : yi);
            term = (double)(sLg[yi] + rc * log1pf(-p) + yv * logf(p));
        }
    }

#pragma unroll
    for (int m = 32; m; m >>= 1) term += __shfl_xor(term, m, 64);
    __shared__ double bl[4];
    if (lane == 0) bl[wib] = term;
    __syncthreads();
    if (t == 0) partials[blockIdx.x] = bl[0] + bl[1] + bl[2] + bl[3];
}

__global__ __launch_bounds__(256) void k_reduce(const double* __restrict__ partials,
                                                int n, float* __restrict__ out) {
    __shared__ double red[NT];
    int t = threadIdx.x;
    double s = 0.0;
    for (int i = t; i < n; i += NT) s += partials[i];
    red[t] = s;
    __syncthreads();
    for (int off = NT / 2; off; off >>= 1) {
        if (t < off) red[t] += red[t + off];
        __syncthreads();
    }
    if (t == 0) out[0] = (float)(-red[0]);
}

extern "C" void kernel_launch(void* const* d_in, const int* in_sizes, int n_in,
                              void* d_out, int out_size, void* d_ws, size_t ws_size,
                              hipStream_t stream) {
    const float* X       = (const float*)d_in[0];
    const float* y       = (const float*)d_in[1];
    const float* Z       = (const float*)d_in[2];
    const float* beta_w  = (const float*)d_in[3];
    const float* gamma_w = (const float*)d_in[4];
    const float* theta   = (const float*)d_in[5];

    const int V       = in_sizes[0] / 256;
    const int n_study = in_sizes[2] / 8;

    float* ws = (float*)d_ws;
    double* partials = (double*)((char*)d_ws + 256);

    const int nwaves  = (V + 63) / 64;
    const int nblocks = (nwaves + 3) / 4;

    k_scalars<<<1, 256, 0, stream>>>(Z, gamma_w, theta, ws, n_study);
    k_main<<<nblocks, 256, 0, stream>>>((const f32x4*)X, y, (const f32x4*)beta_w,
                                        ws, partials, V);
    k_reduce<<<1, 256, 0, stream>>>(partials, nblocks, (float*)d_out);
}

// Round 7
// 63.787 us; speedup vs baseline: 1.1453x; 1.1453x over previous
//
#include <hip/hip_runtime.h>
#include <math.h>

// d_in order: X[300000,256] f32, y[300000,1] f32, Z[1000,8] f32,
//             beta_w[1,256] f32, gamma_w[1,8] f32, theta[1] f32
// ws layout (bytes): [0..15] floats {s1,s2,v,r}; [256..] double partials[nblocks]

typedef float f32x4 __attribute__((ext_vector_type(4)));
#define NT 256

// Single-wave scalar kernel: no LDS, no barriers, shuffle-only reduce.
__global__ __launch_bounds__(64) void k_scalars(const f32x4* __restrict__ Z4,
                                                const f32x4* __restrict__ gamma4,
                                                const float* __restrict__ theta,
                                                float* __restrict__ ws,
                                                int n_study) {
    const int lane = threadIdx.x;
    const f32x4 g0 = gamma4[0], g1 = gamma4[1];
    double s1 = 0.0, s2 = 0.0;
    for (int s = lane; s < n_study; s += 64) {
        f32x4 za = Z4[2 * s], zb = Z4[2 * s + 1];
        float dz = fmaf(za.x, g0.x, fmaf(za.y, g0.y, fmaf(za.z, g0.z, za.w * g0.w)));
        dz = fmaf(zb.x, g1.x, fmaf(zb.y, g1.y, fmaf(zb.z, g1.z, fmaf(zb.w, g1.w, dz))));
        float mz = expf(dz);
        s1 += (double)mz;
        s2 += (double)mz * (double)mz;
    }
#pragma unroll
    for (int m = 32; m; m >>= 1) {
        s1 += __shfl_xor(s1, m, 64);
        s2 += __shfl_xor(s2, m, 64);
    }
    if (lane == 0) {
        const double S1 = s1, S2 = s2;
        const double sig   = 1.0 / (1.0 + exp(-(double)theta[0]));
        const double alpha = 100.0 * (double)n_study * sig + 1e-8;
        const double est   = alpha * S2 / (S1 * S1);  // mean(voxel_sum_alpha), voxel-independent
        const double v     = 1.0 / est;
        const double r     = v * S1 * S1 / S2;
        ws[0] = (float)S1;
        ws[1] = (float)S2;
        ws[2] = (float)v;
        ws[3] = (float)r;
    }
}

__global__ __launch_bounds__(256) void k_main(const f32x4* __restrict__ X4,
                                              const float* __restrict__ y,
                                              const f32x4* __restrict__ beta4,
                                              const float* __restrict__ ws,
                                              double* __restrict__ partials,
                                              int V) {
    const int t    = threadIdx.x;
    const int lane = t & 63;
    const int wib  = t >> 6;

    const float s1c = ws[0], s2c = ws[1], vc = ws[2], rc = ws[3];

    const int wave = blockIdx.x * 4 + wib;
    const int row0 = wave << 6;
    double term = 0.0;

    if (row0 + 64 <= V) {
        const f32x4 b = beta4[lane];
        const f32x4* Xp = X4 + (size_t)row0 * 64 + lane;
        float dmine = 0.f;
        f32x4 xv[8], xn[8];
#pragma unroll
        for (int i = 0; i < 8; ++i) xv[i] = __builtin_nontemporal_load(Xp + i * 64);
#pragma unroll
        for (int bb = 0; bb < 8; ++bb) {
            if (bb < 7) {
#pragma unroll
                for (int i = 0; i < 8; ++i)
                    xn[i] = __builtin_nontemporal_load(Xp + ((bb + 1) * 8 + i) * 64);
            }
            float d[8];
#pragma unroll
            for (int i = 0; i < 8; ++i)
                d[i] = fmaf(xv[i].x, b.x, fmaf(xv[i].y, b.y, fmaf(xv[i].z, b.z, xv[i].w * b.w)));
            // 3-level pairwise transpose-tree: every lane ends with the
            // 8-lane-group partial of row (8*bb + (lane&7)).
#pragma unroll
            for (int s = 1; s < 8; s <<= 1) {
#pragma unroll
                for (int j = 0; j < 8; j += 2 * s) {
                    float ta = __shfl_xor(d[j], s, 64);
                    float tb = __shfl_xor(d[j + s], s, 64);
                    d[j] = (lane & s) ? (d[j + s] + tb) : (d[j] + ta);
                }
            }
            float rs = d[0];
            rs += __shfl_xor(rs, 8, 64);
            rs += __shfl_xor(rs, 16, 64);
            rs += __shfl_xor(rs, 32, 64);   // full row sum, replicated per lane
            if ((lane >> 3) == bb) dmine = rs;  // lane l owns row row0+l
#pragma unroll
            for (int i = 0; i < 8; ++i) xv[i] = xn[i];
        }
        const float yv = y[row0 + lane];
        const float mu = expf(dmine);
        const float num = mu * mu * s2c;
        const float p = num / fmaf(vc * s1c, mu, num);
        float tl = rc * log1pf(-p) + yv * logf(p);
        const int yi = (int)yv;                     // y in {0..5}
        for (int k = 0; k < yi; ++k)                // lgamma(y+r)-lgamma(r)-lgamma(y+1)
            tl += logf((rc + (float)k) / (float)(k + 1));
        term = (double)tl;
    } else if (row0 < V) {  // tail wave
        const f32x4 b = beta4[lane];
        const int nrows = V - row0;
        const f32x4* Xp = X4 + (size_t)row0 * 64 + lane;
        float dmine = 0.f;
        for (int rr = 0; rr < nrows; ++rr) {
            f32x4 x = Xp[(size_t)rr * 64];
            float dd = fmaf(x.x, b.x, fmaf(x.y, b.y, fmaf(x.z, b.z, x.w * b.w)));
#pragma unroll
            for (int m = 32; m; m >>= 1) dd += __shfl_xor(dd, m, 64);
            if (lane == rr) dmine = dd;
        }
        if (lane < nrows) {
            const float yv = y[row0 + lane];
            const float mu = expf(dmine);
            const float num = mu * mu * s2c;
            const float p = num / fmaf(vc * s1c, mu, num);
            float tl = rc * log1pf(-p) + yv * logf(p);
            const int yi = (int)yv;
            for (int k = 0; k < yi; ++k)
                tl += logf((rc + (float)k) / (float)(k + 1));
            term = (double)tl;
        }
    }

#pragma unroll
    for (int m = 32; m; m >>= 1) term += __shfl_xor(term, m, 64);
    __shared__ double bl[4];
    if (lane == 0) bl[wib] = term;
    __syncthreads();
    if (t == 0) partials[blockIdx.x] = bl[0] + bl[1] + bl[2] + bl[3];
}

__global__ __launch_bounds__(256) void k_reduce(const double* __restrict__ partials,
                                                int n, float* __restrict__ out) {
    __shared__ double red[NT];
    int t = threadIdx.x;
    double s = 0.0;
    for (int i = t; i < n; i += NT) s += partials[i];
    red[t] = s;
    __syncthreads();
    for (int off = NT / 2; off; off >>= 1) {
        if (t < off) red[t] += red[t + off];
        __syncthreads();
    }
    if (t == 0) out[0] = (float)(-red[0]);
}

extern "C" void kernel_launch(void* const* d_in, const int* in_sizes, int n_in,
                              void* d_out, int out_size, void* d_ws, size_t ws_size,
                              hipStream_t stream) {
    const float* X       = (const float*)d_in[0];
    const float* y       = (const float*)d_in[1];
    const float* Z       = (const float*)d_in[2];
    const float* beta_w  = (const float*)d_in[3];
    const float* gamma_w = (const float*)d_in[4];
    const float* theta   = (const float*)d_in[5];

    const int V       = in_sizes[0] / 256;
    const int n_study = in_sizes[2] / 8;

    float* ws = (float*)d_ws;
    double* partials = (double*)((char*)d_ws + 256);

    const int nwaves  = (V + 63) / 64;
    const int nblocks = (nwaves + 3) / 4;

    k_scalars<<<1, 64, 0, stream>>>((const f32x4*)Z, (const f32x4*)gamma_w, theta,
                                    ws, n_study);
    k_main<<<nblocks, 256, 0, stream>>>((const f32x4*)X, y, (const f32x4*)beta_w,
                                        ws, partials, V);
    k_reduce<<<1, 256, 0, stream>>>(partials, nblocks, (float*)d_out);
}